// Round 6
// baseline (179.107 us; speedup 1.0000x reference)
//
#include <hip/hip_runtime.h>
#include <hip/hip_bf16.h>

typedef __bf16 bf16;
typedef bf16 bf16x8 __attribute__((ext_vector_type(8)));
typedef float floatx4 __attribute__((ext_vector_type(4)));

// ---------------------------------------------------------------------------
// GEMM: C[m][n] = sum_k A[m][k] * W[n][k]  (+ bias[n] if bias != null)
// A: [M][lda] (f32 if AF32 else bf16), W: [N][K] (f32 if WF32 else bf16),
// C: [M][ldc] of CT (float or bf16). 128x128 tile, BK=32, 256 thr (4 waves),
// 4x4 16x16x32 bf16 MFMA per wave, f32 accumulate.
// MFMA core + epilogue verified equivalent to scalar reference GEMM (R4==R5).
// ---------------------------------------------------------------------------
template<typename CT, bool AF32, bool WF32>
__global__ __launch_bounds__(256)
void gemm_bt(const void* __restrict__ Av, const void* __restrict__ Wv,
             CT* __restrict__ C, const float* __restrict__ bias,
             int M, int N, int K, int lda, int ldc)
{
    __shared__ bf16 As[128 * 32];
    __shared__ bf16 Bs[128 * 32];

    const int tid  = threadIdx.x;
    const int lane = tid & 63;
    const int wave = tid >> 6;
    const int row0 = blockIdx.x * 128;
    const int col0 = blockIdx.y * 128;

    const int wm = (wave & 1) * 64;     // wave sub-tile 64x64
    const int wn = (wave >> 1) * 64;

    floatx4 acc[4][4] = {};

    const int fr = lane & 15;           // A-frag: m = lane&15
    const int fk = (lane >> 4) * 8;     //         k = (lane>>4)*8 + j

    for (int k0 = 0; k0 < K; k0 += 32) {
        // stage 128x32 tiles: 512 x 8-element chunks each, 2 per thread
        #pragma unroll
        for (int c = 0; c < 2; ++c) {
            const int idx = tid + c * 256;   // 0..511
            const int r   = idx >> 2;        // tile row 0..127
            const int cb  = (idx & 3) * 8;   // k-offset 0,8,16,24

            bf16x8 va, vw;
            if (AF32) {
                const float4* g = (const float4*)((const float*)Av
                                   + (size_t)(row0 + r) * lda + k0 + cb);
                float4 g0 = g[0], g1 = g[1];
                va[0] = (bf16)g0.x; va[1] = (bf16)g0.y;
                va[2] = (bf16)g0.z; va[3] = (bf16)g0.w;
                va[4] = (bf16)g1.x; va[5] = (bf16)g1.y;
                va[6] = (bf16)g1.z; va[7] = (bf16)g1.w;
            } else {
                va = *(const bf16x8*)((const bf16*)Av
                                   + (size_t)(row0 + r) * lda + k0 + cb);
            }
            if (WF32) {
                const float4* g = (const float4*)((const float*)Wv
                                   + (size_t)(col0 + r) * K + k0 + cb);
                float4 g0 = g[0], g1 = g[1];
                vw[0] = (bf16)g0.x; vw[1] = (bf16)g0.y;
                vw[2] = (bf16)g0.z; vw[3] = (bf16)g0.w;
                vw[4] = (bf16)g1.x; vw[5] = (bf16)g1.y;
                vw[6] = (bf16)g1.z; vw[7] = (bf16)g1.w;
            } else {
                vw = *(const bf16x8*)((const bf16*)Wv
                                   + (size_t)(col0 + r) * K + k0 + cb);
            }
            *(bf16x8*)(As + r * 32 + cb) = va;
            *(bf16x8*)(Bs + r * 32 + cb) = vw;
        }
        __syncthreads();

        bf16x8 af[4], bfr[4];
        #pragma unroll
        for (int i = 0; i < 4; ++i) {
            af[i]  = *(const bf16x8*)(As + (wm + i * 16 + fr) * 32 + fk);
            bfr[i] = *(const bf16x8*)(Bs + (wn + i * 16 + fr) * 32 + fk);
        }
        #pragma unroll
        for (int i = 0; i < 4; ++i)
            #pragma unroll
            for (int j = 0; j < 4; ++j)
                acc[i][j] = __builtin_amdgcn_mfma_f32_16x16x32_bf16(
                    af[i], bfr[j], acc[i][j], 0, 0, 0);

        __syncthreads();
    }

    // epilogue: D col = lane&15 (n), row = (lane>>4)*4 + reg (m)
    const int fc  = lane & 15;
    const int fr4 = (lane >> 4) * 4;
    #pragma unroll
    for (int i = 0; i < 4; ++i) {
        #pragma unroll
        for (int j = 0; j < 4; ++j) {
            const int col = col0 + wn + j * 16 + fc;
            const float b = bias ? bias[col] : 0.0f;
            #pragma unroll
            for (int r = 0; r < 4; ++r) {
                const int row = row0 + wm + i * 16 + fr4 + r;
                C[(size_t)row * ldc + col] = (CT)(acc[i][j][r] + b);
            }
        }
    }
}

// ---------------------------------------------------------------------------
// Local-window attention, in-place: reads q/k/v from qkv [B*N][2304] (bf16),
// writes output into the q slot (only the owning wave ever reads that q).
// One wave per (b, i, h); lane = d (Dh = 64). Window |i-j| <= 7.
// ---------------------------------------------------------------------------
__global__ __launch_bounds__(256)
void attn_local(bf16* __restrict__ qkv)
{
    const int lane = threadIdx.x & 63;
    const int wid  = (blockIdx.x * blockDim.x + threadIdx.x) >> 6; // (b*N+i)*12+h
    const int h  = wid % 12;
    const int bi = wid / 12;          // b*N + i
    const int i  = bi & 2047;
    const int bbase = bi - i;         // b*N

    const size_t RS = 2304;
    bf16*       qp   = qkv + (size_t)bi * RS + h * 64 + lane;
    const bf16* kcol = qkv + 768  + h * 64 + lane;
    const bf16* vcol = qkv + 1536 + h * 64 + lane;

    const float q = (float)(*qp);

    float s[15];
    #pragma unroll
    for (int jj = 0; jj < 15; ++jj) {
        int j  = i + jj - 7;
        int jc = j < 0 ? 0 : (j > 2047 ? 2047 : j);
        float kv = (float)kcol[(size_t)(bbase + jc) * RS];
        float p = q * kv;
        #pragma unroll
        for (int m = 1; m < 64; m <<= 1) p += __shfl_xor(p, m, 64);
        s[jj] = (j == jc) ? p * 0.125f : -1e30f;
    }

    float mx = s[0];
    #pragma unroll
    for (int jj = 1; jj < 15; ++jj) mx = fmaxf(mx, s[jj]);

    float l = 0.0f, acc = 0.0f;
    #pragma unroll
    for (int jj = 0; jj < 15; ++jj) {
        int j  = i + jj - 7;
        int jc = j < 0 ? 0 : (j > 2047 ? 2047 : j);
        float p = __expf(s[jj] - mx);   // masked -> exp(-huge) == 0
        float vv = (float)vcol[(size_t)(bbase + jc) * RS];
        l   += p;
        acc += p * vv;
    }
    *qp = (bf16)(acc / l);   // in-place into the q slot
}

// ---------------------------------------------------------------------------
extern "C" void kernel_launch(void* const* d_in, const int* in_sizes, int n_in,
                              void* d_out, int out_size, void* d_ws, size_t ws_size,
                              hipStream_t stream)
{
    const float* x      = (const float*)d_in[0];  // [4096][768] f32
    const float* w_qkv  = (const float*)d_in[1];  // [2304][768] f32
    const float* w_proj = (const float*)d_in[2];  // [768][768]  f32
    const float* b_proj = (const float*)d_in[3];  // [768]       f32
    float* out = (float*)d_out;                   // [4096][768] f32  <-- FIXED

    bf16* qkv = (bf16*)d_ws;                      // [4096][2304] bf16, 18.9 MB

    // 1) qkv = bf16(x) @ bf16(w_qkv)^T   (f32 inputs, bf16 MFMA, bf16 store)
    gemm_bt<bf16, true, true><<<dim3(32, 18), 256, 0, stream>>>(
        x, w_qkv, qkv, nullptr, 4096, 2304, 768, 768, 2304);

    // 2) local-window attention, output in-place into q slots
    attn_local<<<dim3(12288), 256, 0, stream>>>(qkv);

    // 3) out = attn(q-slots, lda=2304) @ bf16(w_proj)^T + b_proj   (f32 store)
    gemm_bt<float, false, true><<<dim3(32, 6), 256, 0, stream>>>(
        qkv, w_proj, out, b_proj, 4096, 768, 768, 2304, 768);
}

// Round 7
// 136.568 us; speedup vs baseline: 1.3115x; 1.3115x over previous
//
#include <hip/hip_runtime.h>
#include <hip/hip_bf16.h>

typedef __bf16 bf16;
typedef bf16 bf16x4 __attribute__((ext_vector_type(4)));
typedef bf16 bf16x8 __attribute__((ext_vector_type(8)));
typedef float floatx4 __attribute__((ext_vector_type(4)));

// ---------------------------------------------------------------------------
// f32 -> bf16 conversion for the three weight/input tensors (float4 granular).
// n0/n1/n2 are in float4 units.
// ---------------------------------------------------------------------------
__global__ __launch_bounds__(256)
void cvt3_f32_bf16(const float* __restrict__ s0, const float* __restrict__ s1,
                   const float* __restrict__ s2, bf16* __restrict__ d0,
                   bf16* __restrict__ d1, bf16* __restrict__ d2,
                   int n0, int n1, int n2)
{
    int t = blockIdx.x * blockDim.x + threadIdx.x;
    const float* s; bf16* d; int i;
    if (t < n0)                { s = s0; d = d0; i = t; }
    else if (t < n0 + n1)      { s = s1; d = d1; i = t - n0; }
    else if (t < n0 + n1 + n2) { s = s2; d = d2; i = t - n0 - n1; }
    else return;
    float4 v = ((const float4*)s)[i];
    bf16x4 o = { (bf16)v.x, (bf16)v.y, (bf16)v.z, (bf16)v.w };
    ((bf16x4*)d)[i] = o;
}

// ---------------------------------------------------------------------------
// GEMM: C[m][n] = sum_k A[m][k] * W[n][k]  (+ bias[n] if bias != null)
// A: [M][lda] (f32 if AF32 else bf16), W: [N][K] (f32 if WF32 else bf16),
// C: [M][ldc] of CT. 128x128 tile, BK=32, 4 waves, 4x4 16x16x32 bf16 MFMA.
// Structure HW-verified in R6 (passed absmax).
// ---------------------------------------------------------------------------
template<typename CT, bool AF32, bool WF32>
__global__ __launch_bounds__(256)
void gemm_bt(const void* __restrict__ Av, const void* __restrict__ Wv,
             CT* __restrict__ C, const float* __restrict__ bias,
             int M, int N, int K, int lda, int ldc)
{
    __shared__ __align__(16) bf16 As[128 * 32];
    __shared__ __align__(16) bf16 Bs[128 * 32];

    const int tid  = threadIdx.x;
    const int lane = tid & 63;
    const int wave = tid >> 6;
    const int row0 = blockIdx.x * 128;
    const int col0 = blockIdx.y * 128;

    const int wm = (wave & 1) * 64;
    const int wn = (wave >> 1) * 64;

    floatx4 acc[4][4] = {};

    const int fr = lane & 15;
    const int fk = (lane >> 4) * 8;

    for (int k0 = 0; k0 < K; k0 += 32) {
        #pragma unroll
        for (int c = 0; c < 2; ++c) {
            const int idx = tid + c * 256;   // 0..511
            const int r   = idx >> 2;
            const int cb  = (idx & 3) * 8;

            bf16x8 va, vw;
            if (AF32) {
                const float4* g = (const float4*)((const float*)Av
                                   + (size_t)(row0 + r) * lda + k0 + cb);
                float4 g0 = g[0], g1 = g[1];
                va[0]=(bf16)g0.x; va[1]=(bf16)g0.y; va[2]=(bf16)g0.z; va[3]=(bf16)g0.w;
                va[4]=(bf16)g1.x; va[5]=(bf16)g1.y; va[6]=(bf16)g1.z; va[7]=(bf16)g1.w;
            } else {
                va = *(const bf16x8*)((const bf16*)Av
                                   + (size_t)(row0 + r) * lda + k0 + cb);
            }
            if (WF32) {
                const float4* g = (const float4*)((const float*)Wv
                                   + (size_t)(col0 + r) * K + k0 + cb);
                float4 g0 = g[0], g1 = g[1];
                vw[0]=(bf16)g0.x; vw[1]=(bf16)g0.y; vw[2]=(bf16)g0.z; vw[3]=(bf16)g0.w;
                vw[4]=(bf16)g1.x; vw[5]=(bf16)g1.y; vw[6]=(bf16)g1.z; vw[7]=(bf16)g1.w;
            } else {
                vw = *(const bf16x8*)((const bf16*)Wv
                                   + (size_t)(col0 + r) * K + k0 + cb);
            }
            *(bf16x8*)(As + r * 32 + cb) = va;
            *(bf16x8*)(Bs + r * 32 + cb) = vw;
        }
        __syncthreads();

        bf16x8 af[4], bfr[4];
        #pragma unroll
        for (int i = 0; i < 4; ++i) {
            af[i]  = *(const bf16x8*)(As + (wm + i * 16 + fr) * 32 + fk);
            bfr[i] = *(const bf16x8*)(Bs + (wn + i * 16 + fr) * 32 + fk);
        }
        #pragma unroll
        for (int i = 0; i < 4; ++i)
            #pragma unroll
            for (int j = 0; j < 4; ++j)
                acc[i][j] = __builtin_amdgcn_mfma_f32_16x16x32_bf16(
                    af[i], bfr[j], acc[i][j], 0, 0, 0);

        __syncthreads();
    }

    const int fc  = lane & 15;
    const int fr4 = (lane >> 4) * 4;
    #pragma unroll
    for (int i = 0; i < 4; ++i) {
        #pragma unroll
        for (int j = 0; j < 4; ++j) {
            const int col = col0 + wn + j * 16 + fc;
            const float b = bias ? bias[col] : 0.0f;
            #pragma unroll
            for (int r = 0; r < 4; ++r) {
                const int row = row0 + wm + i * 16 + fr4 + r;
                C[(size_t)row * ldc + col] = (CT)(acc[i][j][r] + b);
            }
        }
    }
}

// ---------------------------------------------------------------------------
// MFMA local-window attention. One wave per (b, h, 16-row i-tile).
// qkv: [B*N][2304] bf16 (q|k|v each [12 heads][64]); writes output in-place
// into the q slot (each tile reads only its own q rows -> race-free).
// Window |i-j| <= 7 -> j-range per 16-i-tile spans 30 <= 32 staged rows:
// single-shot softmax (no online rescale). Layouts per R6-validated MFMA maps:
// A[m=lane&15][k=quad*8+j], B[n=lane&15][k=quad*8+j], C col=lane&15,
// row=quad*4+reg.
// ---------------------------------------------------------------------------
__global__ __launch_bounds__(256)
void attn_tile(bf16* __restrict__ qkv)
{
    // padded strides: 72 elem (144 B) / 40 elem (80 B) keep b128 reads at the
    // 8-lane-per-bank-window optimum and 16 B alignment.
    __shared__ __align__(16) bf16 Ks[4][32][72];
    __shared__ __align__(16) bf16 Vt[4][64][40];
    __shared__ __align__(16) bf16 Ps[4][16][40];

    const int w    = threadIdx.x >> 6;
    const int lane = threadIdx.x & 63;
    const int c    = lane & 15;
    const int q    = lane >> 4;
    const int wid  = blockIdx.x * 4 + w;   // 0..3071
    const int it   = wid & 127;
    const int bh   = wid >> 7;             // 0..23
    const int h    = bh % 12;
    const int b    = bh / 12;
    const int I0   = it * 16;
    const int bbase = b * 2048;
    const int j0   = I0 - 7;

    // ---- stage K rows j0..j0+31 (clamped) and V^T ----
    #pragma unroll
    for (int itr = 0; itr < 4; ++itr) {
        int idx = itr * 64 + lane;        // 0..255
        int row = idx >> 3;               // 0..31
        int dc  = (idx & 7) * 8;          // 0,8,...,56
        int jc  = j0 + row; jc = jc < 0 ? 0 : (jc > 2047 ? 2047 : jc);
        const bf16* base = qkv + (size_t)(bbase + jc) * 2304 + h * 64 + dc;
        bf16x8 kv = *(const bf16x8*)(base + 768);
        bf16x8 vv = *(const bf16x8*)(base + 1536);
        *(bf16x8*)(&Ks[w][row][dc]) = kv;
        #pragma unroll
        for (int e = 0; e < 8; ++e) Vt[w][dc + e][row] = vv[e];
    }

    // Q fragments (A-layout) direct from global: m = c (i-row), k = q*8+j
    const bf16* qrow = qkv + (size_t)(bbase + I0 + c) * 2304 + h * 64;
    bf16x8 aq0 = *(const bf16x8*)(qrow + q * 8);        // d 0..31
    bf16x8 aq1 = *(const bf16x8*)(qrow + 32 + q * 8);   // d 32..63

    __syncthreads();

    // ---- S = Q K^T  (two 16-wide j-tiles, K=64 via 2 chained MFMAs) ----
    floatx4 st[2] = {};
    #pragma unroll
    for (int t = 0; t < 2; ++t) {
        bf16x8 k0 = *(const bf16x8*)(&Ks[w][t * 16 + c][q * 8]);
        bf16x8 k1 = *(const bf16x8*)(&Ks[w][t * 16 + c][32 + q * 8]);
        st[t] = __builtin_amdgcn_mfma_f32_16x16x32_bf16(aq0, k0, st[t], 0, 0, 0);
        st[t] = __builtin_amdgcn_mfma_f32_16x16x32_bf16(aq1, k1, st[t], 0, 0, 0);
    }

    // ---- mask + scale;  C-layout: row i_local = q*4+r, col j_local = t*16+c
    float s[2][4];
    #pragma unroll
    for (int t = 0; t < 2; ++t)
        #pragma unroll
        for (int r = 0; r < 4; ++r) {
            int il = q * 4 + r;
            int jl = t * 16 + c;
            int ja = j0 + jl;
            bool valid = (jl >= il) && (jl <= il + 14) && (ja >= 0) && (ja < 2048);
            s[t][r] = valid ? st[t][r] * 0.125f : -1e30f;
        }

    // ---- softmax (reduce across the 16 col-lanes; masks<16 stay in-group)
    float mx[4], l[4], p[2][4];
    #pragma unroll
    for (int r = 0; r < 4; ++r) {
        float m2 = fmaxf(s[0][r], s[1][r]);
        #pragma unroll
        for (int mk = 1; mk < 16; mk <<= 1) m2 = fmaxf(m2, __shfl_xor(m2, mk, 64));
        mx[r] = m2;
        p[0][r] = __expf(s[0][r] - m2);
        p[1][r] = __expf(s[1][r] - m2);
        float l2 = p[0][r] + p[1][r];
        #pragma unroll
        for (int mk = 1; mk < 16; mk <<= 1) l2 += __shfl_xor(l2, mk, 64);
        l[r] = l2;                       // >= 1 (diagonal always valid)
    }

    // ---- P to LDS (C-layout -> A-layout round-trip), bf16 unnormalized ----
    #pragma unroll
    for (int r = 0; r < 4; ++r) {
        Ps[w][q * 4 + r][c]      = (bf16)p[0][r];
        Ps[w][q * 4 + r][16 + c] = (bf16)p[1][r];
    }
    __syncthreads();

    // ---- O = P V  (K=32 covers all staged j; masked P contribute 0) ----
    bf16x8 ap = *(const bf16x8*)(&Ps[w][c][q * 8]);
    floatx4 ov[4];
    #pragma unroll
    for (int nt = 0; nt < 4; ++nt) {
        bf16x8 vf = *(const bf16x8*)(&Vt[w][nt * 16 + c][q * 8]);
        floatx4 z = {};
        ov[nt] = __builtin_amdgcn_mfma_f32_16x16x32_bf16(ap, vf, z, 0, 0, 0);
    }

    // ---- epilogue: divide by l, write into q slots ----
    float rl[4];
    #pragma unroll
    for (int r = 0; r < 4; ++r) rl[r] = 1.0f / l[r];
    #pragma unroll
    for (int r = 0; r < 4; ++r) {
        bf16* orow = qkv + (size_t)(bbase + I0 + q * 4 + r) * 2304 + h * 64;
        #pragma unroll
        for (int nt = 0; nt < 4; ++nt)
            orow[nt * 16 + c] = (bf16)(ov[nt][r] * rl[r]);
    }
}

// ---------------------------------------------------------------------------
extern "C" void kernel_launch(void* const* d_in, const int* in_sizes, int n_in,
                              void* d_out, int out_size, void* d_ws, size_t ws_size,
                              hipStream_t stream)
{
    const float* x      = (const float*)d_in[0];  // [4096][768] f32
    const float* w_qkv  = (const float*)d_in[1];  // [2304][768] f32
    const float* w_proj = (const float*)d_in[2];  // [768][768]  f32
    const float* b_proj = (const float*)d_in[3];  // [768]       f32
    float* out = (float*)d_out;                   // [4096][768] f32

    bf16* qkv = (bf16*)d_ws;                      // [4096][2304] bf16, 18.87 MB
    const size_t QKV_B  = (size_t)4096 * 2304 * 2;
    const size_t XB_B   = (size_t)4096 * 768 * 2;
    const size_t WQKV_B = (size_t)2304 * 768 * 2;
    const size_t WPRJ_B = (size_t)768 * 768 * 2;

    if (ws_size >= QKV_B + XB_B + WQKV_B + WPRJ_B) {
        // main path: pre-convert inputs to bf16, run bf16-only GEMMs
        bf16* xb  = (bf16*)((char*)d_ws + QKV_B);
        bf16* wqb = (bf16*)((char*)xb + XB_B);
        bf16* wpb = (bf16*)((char*)wqb + WQKV_B);

        const int n0 = 4096 * 768 / 4, n1 = 2304 * 768 / 4, n2 = 768 * 768 / 4;
        cvt3_f32_bf16<<<dim3((n0 + n1 + n2) / 256), 256, 0, stream>>>(
            x, w_qkv, w_proj, xb, wqb, wpb, n0, n1, n2);

        gemm_bt<bf16, false, false><<<dim3(32, 18), 256, 0, stream>>>(
            xb, wqb, qkv, nullptr, 4096, 2304, 768, 768, 2304);

        attn_tile<<<dim3(768), 256, 0, stream>>>(qkv);

        gemm_bt<float, false, false><<<dim3(32, 6), 256, 0, stream>>>(
            qkv, wpb, out, b_proj, 4096, 768, 768, 2304, 768);
    } else {
        // fallback (R6-proven): f32 cvt inside GEMM staging
        gemm_bt<bf16, true, true><<<dim3(32, 18), 256, 0, stream>>>(
            x, w_qkv, qkv, nullptr, 4096, 2304, 768, 768, 2304);

        attn_tile<<<dim3(768), 256, 0, stream>>>(qkv);

        gemm_bt<float, false, true><<<dim3(32, 6), 256, 0, stream>>>(
            qkv, w_proj, out, b_proj, 4096, 768, 768, 2304, 768);
    }
}

// Round 8
// 134.827 us; speedup vs baseline: 1.3284x; 1.0129x over previous
//
#include <hip/hip_runtime.h>
#include <hip/hip_bf16.h>

typedef __bf16 bf16;
typedef bf16 bf16x4 __attribute__((ext_vector_type(4)));
typedef bf16 bf16x8 __attribute__((ext_vector_type(8)));
typedef float floatx4 __attribute__((ext_vector_type(4)));

#define GLOBAL_AS __attribute__((address_space(1)))
#define LDS_AS __attribute__((address_space(3)))

// ---------------------------------------------------------------------------
// f32 -> bf16 conversion for x, w_qkv, w_proj (float4 granular).
// ---------------------------------------------------------------------------
__global__ __launch_bounds__(256)
void cvt3_f32_bf16(const float* __restrict__ s0, const float* __restrict__ s1,
                   const float* __restrict__ s2, bf16* __restrict__ d0,
                   bf16* __restrict__ d1, bf16* __restrict__ d2,
                   int n0, int n1, int n2)
{
    int t = blockIdx.x * blockDim.x + threadIdx.x;
    const float* s; bf16* d; int i;
    if (t < n0)                { s = s0; d = d0; i = t; }
    else if (t < n0 + n1)      { s = s1; d = d1; i = t - n0; }
    else if (t < n0 + n1 + n2) { s = s2; d = d2; i = t - n0 - n1; }
    else return;
    float4 v = ((const float4*)s)[i];
    bf16x4 o = { (bf16)v.x, (bf16)v.y, (bf16)v.z, (bf16)v.w };
    ((bf16x4*)d)[i] = o;
}

// ---------------------------------------------------------------------------
// GEMM: C[m][n] = sum_k A[m][k] * W[n][k]  (+ bias[n] if bias != null)
// A: [M][lda] (f32 if AF32 else bf16), W: [N][K] (f32 if WF32 else bf16),
// C: [M][ldc] of CT. 128x128 tile, BK=32, 4 waves, 4x4 16x16x32 bf16 MFMA.
// bf16 path stages via global_load_lds width=16 (m97 structure; LDS dest is
// wave-uniform base + lane*16B — chunk layout satisfies this exactly).
// ---------------------------------------------------------------------------
template<typename CT, bool AF32, bool WF32>
__global__ __launch_bounds__(256)
void gemm_bt(const void* __restrict__ Av, const void* __restrict__ Wv,
             CT* __restrict__ C, const float* __restrict__ bias,
             int M, int N, int K, int lda, int ldc)
{
    __shared__ __align__(16) bf16 As[128 * 32];
    __shared__ __align__(16) bf16 Bs[128 * 32];

    const int tid  = threadIdx.x;
    const int lane = tid & 63;
    const int wave = tid >> 6;
    const int row0 = blockIdx.x * 128;
    const int col0 = blockIdx.y * 128;

    const int wm = (wave & 1) * 64;
    const int wn = (wave >> 1) * 64;

    floatx4 acc[4][4] = {};

    const int fr = lane & 15;
    const int fk = (lane >> 4) * 8;

    // async-staging address components (bf16 path)
    const int lr = lane >> 2;        // row within 16-row chunk
    const int lk = (lane & 3) * 8;   // k offset within row

    for (int k0 = 0; k0 < K; k0 += 32) {
        if (!AF32 && !WF32) {
            // async global->LDS: each wave stages chunks 2w,2w+1 of A and W.
            // chunk = 16 rows x 32 elem = 1024 B = 64 lanes x 16 B;
            // lane l's 16 B -> chunkbase + l*16 == element l*8 == (l>>2)*32+(l&3)*8.
            #pragma unroll
            for (int c = 0; c < 2; ++c) {
                const int chunk = wave * 2 + c;
                const int r = chunk * 16 + lr;
                const bf16* gA = (const bf16*)Av + (size_t)(row0 + r) * lda + k0 + lk;
                const bf16* gB = (const bf16*)Wv + (size_t)(col0 + r) * K + k0 + lk;
                __builtin_amdgcn_global_load_lds((const GLOBAL_AS void*)gA,
                                                 (LDS_AS void*)(As + chunk * 512),
                                                 16, 0, 0);
                __builtin_amdgcn_global_load_lds((const GLOBAL_AS void*)gB,
                                                 (LDS_AS void*)(Bs + chunk * 512),
                                                 16, 0, 0);
            }
        } else {
            // f32 fallback staging (R6-proven): load, cvt, store to LDS
            #pragma unroll
            for (int c = 0; c < 2; ++c) {
                const int idx = tid + c * 256;   // 0..511
                const int r   = idx >> 2;
                const int cb  = (idx & 3) * 8;

                bf16x8 va, vw;
                if (AF32) {
                    const float4* g = (const float4*)((const float*)Av
                                       + (size_t)(row0 + r) * lda + k0 + cb);
                    float4 g0 = g[0], g1 = g[1];
                    va[0]=(bf16)g0.x; va[1]=(bf16)g0.y; va[2]=(bf16)g0.z; va[3]=(bf16)g0.w;
                    va[4]=(bf16)g1.x; va[5]=(bf16)g1.y; va[6]=(bf16)g1.z; va[7]=(bf16)g1.w;
                } else {
                    va = *(const bf16x8*)((const bf16*)Av
                                       + (size_t)(row0 + r) * lda + k0 + cb);
                }
                if (WF32) {
                    const float4* g = (const float4*)((const float*)Wv
                                       + (size_t)(col0 + r) * K + k0 + cb);
                    float4 g0 = g[0], g1 = g[1];
                    vw[0]=(bf16)g0.x; vw[1]=(bf16)g0.y; vw[2]=(bf16)g0.z; vw[3]=(bf16)g0.w;
                    vw[4]=(bf16)g1.x; vw[5]=(bf16)g1.y; vw[6]=(bf16)g1.z; vw[7]=(bf16)g1.w;
                } else {
                    vw = *(const bf16x8*)((const bf16*)Wv
                                       + (size_t)(col0 + r) * K + k0 + cb);
                }
                *(bf16x8*)(As + r * 32 + cb) = va;
                *(bf16x8*)(Bs + r * 32 + cb) = vw;
            }
        }
        __syncthreads();   // vmcnt(0) drain: tiles resident

        bf16x8 af[4], bfr[4];
        #pragma unroll
        for (int i = 0; i < 4; ++i) {
            af[i]  = *(const bf16x8*)(As + (wm + i * 16 + fr) * 32 + fk);
            bfr[i] = *(const bf16x8*)(Bs + (wn + i * 16 + fr) * 32 + fk);
        }
        #pragma unroll
        for (int i = 0; i < 4; ++i)
            #pragma unroll
            for (int j = 0; j < 4; ++j)
                acc[i][j] = __builtin_amdgcn_mfma_f32_16x16x32_bf16(
                    af[i], bfr[j], acc[i][j], 0, 0, 0);

        __syncthreads();   // all ds_reads done before next overwrite
    }

    const int fc  = lane & 15;
    const int fr4 = (lane >> 4) * 4;
    #pragma unroll
    for (int i = 0; i < 4; ++i) {
        #pragma unroll
        for (int j = 0; j < 4; ++j) {
            const int col = col0 + wn + j * 16 + fc;
            const float b = bias ? bias[col] : 0.0f;
            #pragma unroll
            for (int r = 0; r < 4; ++r) {
                const int row = row0 + wm + i * 16 + fr4 + r;
                C[(size_t)row * ldc + col] = (CT)(acc[i][j][r] + b);
            }
        }
    }
}

// ---------------------------------------------------------------------------
// MFMA local-window attention (unchanged from R7 — HW-verified).
// One wave per (b, h, 16-row i-tile); writes in-place into the q slot.
// ---------------------------------------------------------------------------
__global__ __launch_bounds__(256)
void attn_tile(bf16* __restrict__ qkv)
{
    __shared__ __align__(16) bf16 Ks[4][32][72];
    __shared__ __align__(16) bf16 Vt[4][64][40];
    __shared__ __align__(16) bf16 Ps[4][16][40];

    const int w    = threadIdx.x >> 6;
    const int lane = threadIdx.x & 63;
    const int c    = lane & 15;
    const int q    = lane >> 4;
    const int wid  = blockIdx.x * 4 + w;   // 0..3071
    const int it   = wid & 127;
    const int bh   = wid >> 7;             // 0..23
    const int h    = bh % 12;
    const int b    = bh / 12;
    const int I0   = it * 16;
    const int bbase = b * 2048;
    const int j0   = I0 - 7;

    #pragma unroll
    for (int itr = 0; itr < 4; ++itr) {
        int idx = itr * 64 + lane;        // 0..255
        int row = idx >> 3;               // 0..31
        int dc  = (idx & 7) * 8;          // 0,8,...,56
        int jc  = j0 + row; jc = jc < 0 ? 0 : (jc > 2047 ? 2047 : jc);
        const bf16* base = qkv + (size_t)(bbase + jc) * 2304 + h * 64 + dc;
        bf16x8 kv = *(const bf16x8*)(base + 768);
        bf16x8 vv = *(const bf16x8*)(base + 1536);
        *(bf16x8*)(&Ks[w][row][dc]) = kv;
        #pragma unroll
        for (int e = 0; e < 8; ++e) Vt[w][dc + e][row] = vv[e];
    }

    const bf16* qrow = qkv + (size_t)(bbase + I0 + c) * 2304 + h * 64;
    bf16x8 aq0 = *(const bf16x8*)(qrow + q * 8);
    bf16x8 aq1 = *(const bf16x8*)(qrow + 32 + q * 8);

    __syncthreads();

    floatx4 st[2] = {};
    #pragma unroll
    for (int t = 0; t < 2; ++t) {
        bf16x8 k0 = *(const bf16x8*)(&Ks[w][t * 16 + c][q * 8]);
        bf16x8 k1 = *(const bf16x8*)(&Ks[w][t * 16 + c][32 + q * 8]);
        st[t] = __builtin_amdgcn_mfma_f32_16x16x32_bf16(aq0, k0, st[t], 0, 0, 0);
        st[t] = __builtin_amdgcn_mfma_f32_16x16x32_bf16(aq1, k1, st[t], 0, 0, 0);
    }

    float s[2][4];
    #pragma unroll
    for (int t = 0; t < 2; ++t)
        #pragma unroll
        for (int r = 0; r < 4; ++r) {
            int il = q * 4 + r;
            int jl = t * 16 + c;
            int ja = j0 + jl;
            bool valid = (jl >= il) && (jl <= il + 14) && (ja >= 0) && (ja < 2048);
            s[t][r] = valid ? st[t][r] * 0.125f : -1e30f;
        }

    float mx[4], l[4], p[2][4];
    #pragma unroll
    for (int r = 0; r < 4; ++r) {
        float m2 = fmaxf(s[0][r], s[1][r]);
        #pragma unroll
        for (int mk = 1; mk < 16; mk <<= 1) m2 = fmaxf(m2, __shfl_xor(m2, mk, 64));
        mx[r] = m2;
        p[0][r] = __expf(s[0][r] - m2);
        p[1][r] = __expf(s[1][r] - m2);
        float l2 = p[0][r] + p[1][r];
        #pragma unroll
        for (int mk = 1; mk < 16; mk <<= 1) l2 += __shfl_xor(l2, mk, 64);
        l[r] = l2;
    }

    #pragma unroll
    for (int r = 0; r < 4; ++r) {
        Ps[w][q * 4 + r][c]      = (bf16)p[0][r];
        Ps[w][q * 4 + r][16 + c] = (bf16)p[1][r];
    }
    __syncthreads();

    bf16x8 ap = *(const bf16x8*)(&Ps[w][c][q * 8]);
    floatx4 ov[4];
    #pragma unroll
    for (int nt = 0; nt < 4; ++nt) {
        bf16x8 vf = *(const bf16x8*)(&Vt[w][nt * 16 + c][q * 8]);
        floatx4 z = {};
        ov[nt] = __builtin_amdgcn_mfma_f32_16x16x32_bf16(ap, vf, z, 0, 0, 0);
    }

    float rl[4];
    #pragma unroll
    for (int r = 0; r < 4; ++r) rl[r] = 1.0f / l[r];
    #pragma unroll
    for (int r = 0; r < 4; ++r) {
        bf16* orow = qkv + (size_t)(bbase + I0 + q * 4 + r) * 2304 + h * 64;
        #pragma unroll
        for (int nt = 0; nt < 4; ++nt)
            orow[nt * 16 + c] = (bf16)(ov[nt][r] * rl[r]);
    }
}

// ---------------------------------------------------------------------------
extern "C" void kernel_launch(void* const* d_in, const int* in_sizes, int n_in,
                              void* d_out, int out_size, void* d_ws, size_t ws_size,
                              hipStream_t stream)
{
    const float* x      = (const float*)d_in[0];  // [4096][768] f32
    const float* w_qkv  = (const float*)d_in[1];  // [2304][768] f32
    const float* w_proj = (const float*)d_in[2];  // [768][768]  f32
    const float* b_proj = (const float*)d_in[3];  // [768]       f32
    float* out = (float*)d_out;                   // [4096][768] f32

    bf16* qkv = (bf16*)d_ws;                      // [4096][2304] bf16, 18.87 MB
    const size_t QKV_B  = (size_t)4096 * 2304 * 2;
    const size_t XB_B   = (size_t)4096 * 768 * 2;
    const size_t WQKV_B = (size_t)2304 * 768 * 2;
    const size_t WPRJ_B = (size_t)768 * 768 * 2;

    if (ws_size >= QKV_B + XB_B + WQKV_B + WPRJ_B) {
        // main path: pre-convert to bf16, async-staged bf16 GEMMs
        bf16* xb  = (bf16*)((char*)d_ws + QKV_B);
        bf16* wqb = (bf16*)((char*)xb + XB_B);
        bf16* wpb = (bf16*)((char*)wqb + WQKV_B);

        const int n0 = 4096 * 768 / 4, n1 = 2304 * 768 / 4, n2 = 768 * 768 / 4;
        cvt3_f32_bf16<<<dim3((n0 + n1 + n2) / 256), 256, 0, stream>>>(
            x, w_qkv, w_proj, xb, wqb, wpb, n0, n1, n2);

        gemm_bt<bf16, false, false><<<dim3(32, 18), 256, 0, stream>>>(
            xb, wqb, qkv, nullptr, 4096, 2304, 768, 768, 2304);

        attn_tile<<<dim3(768), 256, 0, stream>>>(qkv);

        gemm_bt<float, false, false><<<dim3(32, 6), 256, 0, stream>>>(
            qkv, wpb, out, b_proj, 4096, 768, 768, 2304, 768);
    } else {
        // fallback (R6-proven): f32 cvt inside GEMM staging
        gemm_bt<bf16, true, true><<<dim3(32, 18), 256, 0, stream>>>(
            x, w_qkv, qkv, nullptr, 4096, 2304, 768, 768, 2304);

        attn_tile<<<dim3(768), 256, 0, stream>>>(qkv);

        gemm_bt<float, false, true><<<dim3(32, 6), 256, 0, stream>>>(
            qkv, w_proj, out, b_proj, 4096, 768, 768, 2304, 768);
    }
}

// Round 9
// 126.616 us; speedup vs baseline: 1.4146x; 1.0649x over previous
//
#include <hip/hip_runtime.h>
#include <hip/hip_bf16.h>

typedef __bf16 bf16;
typedef bf16 bf16x4 __attribute__((ext_vector_type(4)));
typedef bf16 bf16x8 __attribute__((ext_vector_type(8)));
typedef float floatx4 __attribute__((ext_vector_type(4)));

#define GLOBAL_AS __attribute__((address_space(1)))
#define LDS_AS __attribute__((address_space(3)))

// ---------------------------------------------------------------------------
// f32 -> bf16 conversion for x, w_qkv, w_proj (float4 granular).
// ---------------------------------------------------------------------------
__global__ __launch_bounds__(256)
void cvt3_f32_bf16(const float* __restrict__ s0, const float* __restrict__ s1,
                   const float* __restrict__ s2, bf16* __restrict__ d0,
                   bf16* __restrict__ d1, bf16* __restrict__ d2,
                   int n0, int n1, int n2)
{
    int t = blockIdx.x * blockDim.x + threadIdx.x;
    const float* s; bf16* d; int i;
    if (t < n0)                { s = s0; d = d0; i = t; }
    else if (t < n0 + n1)      { s = s1; d = d1; i = t - n0; }
    else if (t < n0 + n1 + n2) { s = s2; d = d2; i = t - n0 - n1; }
    else return;
    float4 v = ((const float4*)s)[i];
    bf16x4 o = { (bf16)v.x, (bf16)v.y, (bf16)v.z, (bf16)v.w };
    ((bf16x4*)d)[i] = o;
}

// ---------------------------------------------------------------------------
// GEMM: C[m][n] = sum_k A[m][k] * W[n][k]  (+ bias[n] if bias != null)
// ALL shapes/strides compile-time. 128x128 tile, BK=32, 4 waves,
// 4x4 16x16x32 bf16 MFMA, f32 accumulate.
// __launch_bounds__(256,2): VGPR <= 256 -> >= 2 blocks/CU guaranteed.
// bf16 path: async global_load_lds(16B) staging; f32 path: cvt-in-staging.
// ---------------------------------------------------------------------------
template<typename CT, bool AF32, bool WF32, int M, int N, int K, int LDA, int LDC>
__global__ __launch_bounds__(256, 2)
void gemm_bt(const void* __restrict__ Av, const void* __restrict__ Wv,
             CT* __restrict__ C, const float* __restrict__ bias)
{
    __shared__ __align__(16) bf16 As[128 * 32];
    __shared__ __align__(16) bf16 Bs[128 * 32];

    const int tid  = threadIdx.x;
    const int lane = tid & 63;
    const int wave = tid >> 6;
    const int row0 = blockIdx.x * 128;
    const int col0 = blockIdx.y * 128;

    const int wm = (wave & 1) * 64;
    const int wn = (wave >> 1) * 64;

    floatx4 acc[4][4] = {};

    const int fr = lane & 15;
    const int fk = (lane >> 4) * 8;

    const int lr = lane >> 2;        // async staging: row within 16-row chunk
    const int lk = (lane & 3) * 8;   //                k offset within row

    for (int k0 = 0; k0 < K; k0 += 32) {
        if (!AF32 && !WF32) {
            // async DMA: chunk = 16 rows x 32 elem = 64 lanes x 16 B;
            // lane l -> chunkbase + l*16 == element l*8 == (l>>2)*32+(l&3)*8.
            #pragma unroll
            for (int c = 0; c < 2; ++c) {
                const int chunk = wave * 2 + c;
                const int r = chunk * 16 + lr;
                const bf16* gA = (const bf16*)Av + (size_t)(row0 + r) * LDA + k0 + lk;
                const bf16* gB = (const bf16*)Wv + (size_t)(col0 + r) * K + k0 + lk;
                __builtin_amdgcn_global_load_lds((const GLOBAL_AS void*)gA,
                                                 (LDS_AS void*)(As + chunk * 512),
                                                 16, 0, 0);
                __builtin_amdgcn_global_load_lds((const GLOBAL_AS void*)gB,
                                                 (LDS_AS void*)(Bs + chunk * 512),
                                                 16, 0, 0);
            }
        } else {
            #pragma unroll
            for (int c = 0; c < 2; ++c) {
                const int idx = tid + c * 256;   // 0..511
                const int r   = idx >> 2;
                const int cb  = (idx & 3) * 8;

                bf16x8 va, vw;
                if (AF32) {
                    const float4* g = (const float4*)((const float*)Av
                                       + (size_t)(row0 + r) * LDA + k0 + cb);
                    float4 g0 = g[0], g1 = g[1];
                    va[0]=(bf16)g0.x; va[1]=(bf16)g0.y; va[2]=(bf16)g0.z; va[3]=(bf16)g0.w;
                    va[4]=(bf16)g1.x; va[5]=(bf16)g1.y; va[6]=(bf16)g1.z; va[7]=(bf16)g1.w;
                } else {
                    va = *(const bf16x8*)((const bf16*)Av
                                       + (size_t)(row0 + r) * LDA + k0 + cb);
                }
                if (WF32) {
                    const float4* g = (const float4*)((const float*)Wv
                                       + (size_t)(col0 + r) * K + k0 + cb);
                    float4 g0 = g[0], g1 = g[1];
                    vw[0]=(bf16)g0.x; vw[1]=(bf16)g0.y; vw[2]=(bf16)g0.z; vw[3]=(bf16)g0.w;
                    vw[4]=(bf16)g1.x; vw[5]=(bf16)g1.y; vw[6]=(bf16)g1.z; vw[7]=(bf16)g1.w;
                } else {
                    vw = *(const bf16x8*)((const bf16*)Wv
                                       + (size_t)(col0 + r) * K + k0 + cb);
                }
                *(bf16x8*)(As + r * 32 + cb) = va;
                *(bf16x8*)(Bs + r * 32 + cb) = vw;
            }
        }
        __syncthreads();

        bf16x8 af[4], bfr[4];
        #pragma unroll
        for (int i = 0; i < 4; ++i) {
            af[i]  = *(const bf16x8*)(As + (wm + i * 16 + fr) * 32 + fk);
            bfr[i] = *(const bf16x8*)(Bs + (wn + i * 16 + fr) * 32 + fk);
        }
        #pragma unroll
        for (int i = 0; i < 4; ++i)
            #pragma unroll
            for (int j = 0; j < 4; ++j)
                acc[i][j] = __builtin_amdgcn_mfma_f32_16x16x32_bf16(
                    af[i], bfr[j], acc[i][j], 0, 0, 0);

        __syncthreads();
    }

    const int fc  = lane & 15;
    const int fr4 = (lane >> 4) * 4;
    #pragma unroll
    for (int i = 0; i < 4; ++i) {
        #pragma unroll
        for (int j = 0; j < 4; ++j) {
            const int col = col0 + wn + j * 16 + fc;
            const float b = bias ? bias[col] : 0.0f;
            #pragma unroll
            for (int r = 0; r < 4; ++r) {
                const int row = row0 + wm + i * 16 + fr4 + r;
                C[(size_t)row * LDC + col] = (CT)(acc[i][j][r] + b);
            }
        }
    }
}

// ---------------------------------------------------------------------------
// MFMA local-window attention (unchanged — HW-verified R7/R8).
// One wave per (b, h, 16-row i-tile); writes in-place into the q slot.
// ---------------------------------------------------------------------------
__global__ __launch_bounds__(256)
void attn_tile(bf16* __restrict__ qkv)
{
    __shared__ __align__(16) bf16 Ks[4][32][72];
    __shared__ __align__(16) bf16 Vt[4][64][40];
    __shared__ __align__(16) bf16 Ps[4][16][40];

    const int w    = threadIdx.x >> 6;
    const int lane = threadIdx.x & 63;
    const int c    = lane & 15;
    const int q    = lane >> 4;
    const int wid  = blockIdx.x * 4 + w;   // 0..3071
    const int it   = wid & 127;
    const int bh   = wid >> 7;             // 0..23
    const int h    = bh % 12;
    const int b    = bh / 12;
    const int I0   = it * 16;
    const int bbase = b * 2048;
    const int j0   = I0 - 7;

    #pragma unroll
    for (int itr = 0; itr < 4; ++itr) {
        int idx = itr * 64 + lane;        // 0..255
        int row = idx >> 3;               // 0..31
        int dc  = (idx & 7) * 8;          // 0,8,...,56
        int jc  = j0 + row; jc = jc < 0 ? 0 : (jc > 2047 ? 2047 : jc);
        const bf16* base = qkv + (size_t)(bbase + jc) * 2304 + h * 64 + dc;
        bf16x8 kv = *(const bf16x8*)(base + 768);
        bf16x8 vv = *(const bf16x8*)(base + 1536);
        *(bf16x8*)(&Ks[w][row][dc]) = kv;
        #pragma unroll
        for (int e = 0; e < 8; ++e) Vt[w][dc + e][row] = vv[e];
    }

    const bf16* qrow = qkv + (size_t)(bbase + I0 + c) * 2304 + h * 64;
    bf16x8 aq0 = *(const bf16x8*)(qrow + q * 8);
    bf16x8 aq1 = *(const bf16x8*)(qrow + 32 + q * 8);

    __syncthreads();

    floatx4 st[2] = {};
    #pragma unroll
    for (int t = 0; t < 2; ++t) {
        bf16x8 k0 = *(const bf16x8*)(&Ks[w][t * 16 + c][q * 8]);
        bf16x8 k1 = *(const bf16x8*)(&Ks[w][t * 16 + c][32 + q * 8]);
        st[t] = __builtin_amdgcn_mfma_f32_16x16x32_bf16(aq0, k0, st[t], 0, 0, 0);
        st[t] = __builtin_amdgcn_mfma_f32_16x16x32_bf16(aq1, k1, st[t], 0, 0, 0);
    }

    float s[2][4];
    #pragma unroll
    for (int t = 0; t < 2; ++t)
        #pragma unroll
        for (int r = 0; r < 4; ++r) {
            int il = q * 4 + r;
            int jl = t * 16 + c;
            int ja = j0 + jl;
            bool valid = (jl >= il) && (jl <= il + 14) && (ja >= 0) && (ja < 2048);
            s[t][r] = valid ? st[t][r] * 0.125f : -1e30f;
        }

    float mx[4], l[4], p[2][4];
    #pragma unroll
    for (int r = 0; r < 4; ++r) {
        float m2 = fmaxf(s[0][r], s[1][r]);
        #pragma unroll
        for (int mk = 1; mk < 16; mk <<= 1) m2 = fmaxf(m2, __shfl_xor(m2, mk, 64));
        mx[r] = m2;
        p[0][r] = __expf(s[0][r] - m2);
        p[1][r] = __expf(s[1][r] - m2);
        float l2 = p[0][r] + p[1][r];
        #pragma unroll
        for (int mk = 1; mk < 16; mk <<= 1) l2 += __shfl_xor(l2, mk, 64);
        l[r] = l2;
    }

    #pragma unroll
    for (int r = 0; r < 4; ++r) {
        Ps[w][q * 4 + r][c]      = (bf16)p[0][r];
        Ps[w][q * 4 + r][16 + c] = (bf16)p[1][r];
    }
    __syncthreads();

    bf16x8 ap = *(const bf16x8*)(&Ps[w][c][q * 8]);
    floatx4 ov[4];
    #pragma unroll
    for (int nt = 0; nt < 4; ++nt) {
        bf16x8 vf = *(const bf16x8*)(&Vt[w][nt * 16 + c][q * 8]);
        floatx4 z = {};
        ov[nt] = __builtin_amdgcn_mfma_f32_16x16x32_bf16(ap, vf, z, 0, 0, 0);
    }

    float rl[4];
    #pragma unroll
    for (int r = 0; r < 4; ++r) rl[r] = 1.0f / l[r];
    #pragma unroll
    for (int r = 0; r < 4; ++r) {
        bf16* orow = qkv + (size_t)(bbase + I0 + q * 4 + r) * 2304 + h * 64;
        #pragma unroll
        for (int nt = 0; nt < 4; ++nt)
            orow[nt * 16 + c] = (bf16)(ov[nt][r] * rl[r]);
    }
}

// ---------------------------------------------------------------------------
extern "C" void kernel_launch(void* const* d_in, const int* in_sizes, int n_in,
                              void* d_out, int out_size, void* d_ws, size_t ws_size,
                              hipStream_t stream)
{
    const float* x      = (const float*)d_in[0];  // [4096][768] f32
    const float* w_qkv  = (const float*)d_in[1];  // [2304][768] f32
    const float* w_proj = (const float*)d_in[2];  // [768][768]  f32
    const float* b_proj = (const float*)d_in[3];  // [768]       f32
    float* out = (float*)d_out;                   // [4096][768] f32

    bf16* qkv = (bf16*)d_ws;                      // [4096][2304] bf16, 18.87 MB
    const size_t QKV_B  = (size_t)4096 * 2304 * 2;
    const size_t XB_B   = (size_t)4096 * 768 * 2;
    const size_t WQKV_B = (size_t)2304 * 768 * 2;
    const size_t WPRJ_B = (size_t)768 * 768 * 2;

    if (ws_size >= QKV_B + XB_B + WQKV_B + WPRJ_B) {
        bf16* xb  = (bf16*)((char*)d_ws + QKV_B);
        bf16* wqb = (bf16*)((char*)xb + XB_B);
        bf16* wpb = (bf16*)((char*)wqb + WQKV_B);

        const int n0 = 4096 * 768 / 4, n1 = 2304 * 768 / 4, n2 = 768 * 768 / 4;
        cvt3_f32_bf16<<<dim3((n0 + n1 + n2) / 256), 256, 0, stream>>>(
            x, w_qkv, w_proj, xb, wqb, wpb, n0, n1, n2);

        gemm_bt<bf16, false, false, 4096, 2304, 768, 768, 2304>
            <<<dim3(32, 18), 256, 0, stream>>>(xb, wqb, qkv, nullptr);

        attn_tile<<<dim3(768), 256, 0, stream>>>(qkv);

        gemm_bt<float, false, false, 4096, 768, 768, 2304, 768>
            <<<dim3(32, 6), 256, 0, stream>>>(qkv, wpb, out, b_proj);
    } else {
        // fallback: f32 cvt inside GEMM staging (R6-proven numerics)
        gemm_bt<bf16, true, true, 4096, 2304, 768, 768, 2304>
            <<<dim3(32, 18), 256, 0, stream>>>(x, w_qkv, qkv, nullptr);

        attn_tile<<<dim3(768), 256, 0, stream>>>(qkv);

        gemm_bt<float, false, true, 4096, 768, 768, 2304, 768>
            <<<dim3(32, 6), 256, 0, stream>>>(qkv, w_proj, out, b_proj);
    }
}